// Round 1
// baseline (451.633 us; speedup 1.0000x reference)
//
#include <hip/hip_runtime.h>
#include <hip/hip_bf16.h>
#include <cstdint>

#define BATCH 64
#define CIN 3
#define IMG 384
#define PATCH 16
#define HID 768
#define CQ 96
#define HW24 24
#define NP 576
#define MROWS (BATCH*NP)   /* 36864 */
#define KDIM 768           /* = CIN*PATCH*PATCH = HID */
#define NEGINF (-1e30f)

typedef __attribute__((ext_vector_type(8))) short s16x8;
typedef __attribute__((ext_vector_type(4))) float f32x4;

__device__ __forceinline__ float bf2f(unsigned short u) {
    union { unsigned int i; float f; } x; x.i = ((unsigned int)u) << 16; return x.f;
}
__device__ __forceinline__ unsigned short f2bf(float f) {
    union { float f; unsigned int i; } x; x.f = f;
    unsigned int r = x.i + 0x7fffu + ((x.i >> 16) & 1u);
    return (unsigned short)(r >> 16);
}

// async global->LDS, 16B per lane. LDS dest must be linear (wave-uniform base + lane*16).
__device__ __forceinline__ void gload_lds16(const void* g, void* l) {
    __builtin_amdgcn_global_load_lds(
        (const __attribute__((address_space(1))) void*)(uintptr_t)g,
        (__attribute__((address_space(3))) void*)(uint32_t)(uintptr_t)l,
        16, 0, 0);
}

// ---------------- im2col: x (B,3,384,384) f32 -> A (36864 x 768) bf16 ----------------
__global__ void k_im2col(const float* __restrict__ x, unsigned short* __restrict__ A) {
    int idx = blockIdx.x * 256 + threadIdx.x;
    const int total = MROWS * KDIM / 4;
    if (idx >= total) return;
    int flat = idx * 4;
    int r = flat / KDIM;
    int cij = flat - r * KDIM;
    int b = r / NP;
    int p = r - b * NP;
    int ph = p / HW24, pw = p - ph * HW24;
    int c = cij >> 8;
    int rem = cij & 255;
    int i = rem >> 4, j = rem & 15;
    size_t xoff = (((size_t)(b * CIN + c) * IMG) + (size_t)(ph * PATCH + i)) * IMG + pw * PATCH + j;
    float4 v = *reinterpret_cast<const float4*>(x + xoff);
    ushort4 o;
    o.x = f2bf(v.x); o.y = f2bf(v.y); o.z = f2bf(v.z); o.w = f2bf(v.w);
    *reinterpret_cast<ushort4*>(A + flat) = o;
}

// ---------------- weight prep: fp32 -> bf16 [N][K]; wq/wk combined+padded to 256 rows ----------------
__global__ void k_prep(const float* __restrict__ pw, const float* __restrict__ wq,
                       const float* __restrict__ wk, const float* __restrict__ wv,
                       const float* __restrict__ bq, const float* __restrict__ bk,
                       unsigned short* __restrict__ Wp, unsigned short* __restrict__ Wqk,
                       unsigned short* __restrict__ Wv, float* __restrict__ Bqk) {
    int t = blockIdx.x * 256 + threadIdx.x;
    if (t < HID * HID) { Wp[t] = f2bf(pw[t]); Wv[t] = f2bf(wv[t]); }
    if (t < 256 * HID) {
        int row = t / HID;
        float val = 0.f;
        if (row < 96) val = wq[t];
        else if (row < 192) val = wk[t - 96 * HID];
        Wqk[t] = f2bf(val);
    }
    if (t < 256) {
        float v = 0.f;
        if (t < 96) v = bq[t]; else if (t < 192) v = bk[t - 96];
        Bqk[t] = v;
    }
}

// ---------------- bf16 GEMM:  C[M][N] = A[M][K] * Bw[N][K]^T + bias[N]   (m97 structure) ----------------
__global__ __launch_bounds__(256) void k_gemm_bt(
    const unsigned short* __restrict__ A, const unsigned short* __restrict__ Bw,
    const float* __restrict__ bias, unsigned short* __restrict__ C,
    int M, int N, int K)
{
    __shared__ unsigned short lA[128 * 32];
    __shared__ unsigned short lB[128 * 32];
    const int tid  = threadIdx.x;
    const int lane = tid & 63;
    const int wid  = tid >> 6;
    const int wr = (wid >> 1) << 6;   // wave row offset (0/64)
    const int wc = (wid & 1) << 6;    // wave col offset (0/64)
    const int srow = tid >> 2;        // staging row 0..63
    const int scol = (tid & 3) << 3;  // staging col 0/8/16/24

    const unsigned short* gA = A + (size_t)(blockIdx.x * 128 + srow) * K + scol;
    const unsigned short* gB = Bw + (size_t)(blockIdx.y * 128 + srow) * K + scol;
    unsigned short* dA0 = &lA[tid * 8];
    unsigned short* dA1 = &lA[tid * 8 + 64 * 32];
    unsigned short* dB0 = &lB[tid * 8];
    unsigned short* dB1 = &lB[tid * 8 + 64 * 32];

    const int abase = (wr + (lane & 15)) * 32 + (lane >> 4) * 8;
    const int bbase = (wc + (lane & 15)) * 32 + (lane >> 4) * 8;

    f32x4 acc[4][4] = {};

    for (int kk = 0; kk < K; kk += 32) {
        gload_lds16(gA, dA0);
        gload_lds16(gA + (size_t)64 * K, dA1);
        gload_lds16(gB, dB0);
        gload_lds16(gB + (size_t)64 * K, dB1);
        gA += 32; gB += 32;
        __syncthreads();   // compiler emits vmcnt(0) drain before s_barrier

        s16x8 af[4], bf[4];
        #pragma unroll
        for (int m = 0; m < 4; m++) af[m] = *(const s16x8*)&lA[abase + m * 16 * 32];
        #pragma unroll
        for (int n = 0; n < 4; n++) bf[n] = *(const s16x8*)&lB[bbase + n * 16 * 32];

        #pragma unroll
        for (int m = 0; m < 4; m++)
            #pragma unroll
            for (int n = 0; n < 4; n++)
                acc[m][n] = __builtin_amdgcn_mfma_f32_16x16x32_bf16(af[m], bf[n], acc[m][n], 0, 0, 0);
        __syncthreads();
    }

    // C/D layout: col = lane&15, row = (lane>>4)*4 + reg   [m89-verified mapping]
    const int colbase = blockIdx.y * 128 + wc + (lane & 15);
    const int rowbase = blockIdx.x * 128 + wr + ((lane >> 4) << 2);
    #pragma unroll
    for (int n = 0; n < 4; n++) {
        int col = colbase + n * 16;
        float bs = bias[col];
        #pragma unroll
        for (int m = 0; m < 4; m++) {
            int row = rowbase + m * 16;
            #pragma unroll
            for (int r2 = 0; r2 < 4; r2++) {
                C[(size_t)(row + r2) * N + col] = f2bf(acc[m][n][r2] + bs);
            }
        }
    }
}

// ---------------- criss-cross attention + epilogue ----------------
// QK: [M][256] bf16 (q in cols 0..95, k in cols 96..191); V,Y: [M][768] bf16
// out[b,p,hid] = gamma*(out_H+out_W) + Y + pos_emb
__global__ __launch_bounds__(256) void k_attn(
    const unsigned short* __restrict__ QK, const unsigned short* __restrict__ V,
    const unsigned short* __restrict__ Y, const float* __restrict__ gamma,
    const float* __restrict__ pos_emb, float* __restrict__ out)
{
    __shared__ float qs[CQ];
    __shared__ float att[48];
    const int tid = threadIdx.x;
    const int pg = blockIdx.x;          // 0..36863
    const int b = pg / NP;
    const int p = pg - b * NP;
    const int h = p / HW24, w = p - h * HW24;

    if (tid < CQ) qs[tid] = bf2f(QK[(size_t)pg * 256 + tid]);
    __syncthreads();

    // 48 energies: j<24 -> H-branch (row j, col w), masked at j==h; j>=24 -> W-branch (row h, col j-24)
    if (tid < 48) {
        float e;
        if (tid < 24 && tid == h) {
            e = NEGINF;
        } else {
            int rj = (tid < 24) ? (b * NP + tid * HW24 + w)
                                : (b * NP + h * HW24 + (tid - 24));
            const unsigned short* krow = QK + (size_t)rj * 256 + 96;
            float s = 0.f;
            for (int c = 0; c < CQ; c += 8) {
                s16x8 kv = *(const s16x8*)(krow + c);
                #pragma unroll
                for (int u = 0; u < 8; u++) s += qs[c + u] * bf2f((unsigned short)kv[u]);
            }
            e = s;
        }
        att[tid] = e;
    }
    __syncthreads();

    // softmax over the 48 (first wave)
    if (tid < 64) {
        float e = (tid < 48) ? att[tid] : NEGINF;
        float mx = e;
        #pragma unroll
        for (int o = 32; o > 0; o >>= 1) mx = fmaxf(mx, __shfl_xor(mx, o));
        float ex = (tid < 48) ? __expf(e - mx) : 0.f;
        float sm = ex;
        #pragma unroll
        for (int o = 32; o > 0; o >>= 1) sm += __shfl_xor(sm, o);
        if (tid < 48) att[tid] = ex / sm;
    }
    __syncthreads();

    // PV + epilogue: thread t owns channels t, t+256, t+512
    float acc0 = 0.f, acc1 = 0.f, acc2 = 0.f;
    const unsigned short* vb = V + (size_t)b * NP * HID;
    for (int jj = 0; jj < 48; jj++) {
        float a = att[jj];
        int row = (jj < 24) ? (jj * HW24 + w) : (h * HW24 + (jj - 24));
        const unsigned short* vr = vb + (size_t)row * HID + tid;
        acc0 += a * bf2f(vr[0]);
        acc1 += a * bf2f(vr[256]);
        acc2 += a * bf2f(vr[512]);
    }
    float g = gamma[0];
    size_t ob = (size_t)pg * HID;
    size_t pb = (size_t)p * HID;
    out[ob + tid]       = g * acc0 + bf2f(Y[ob + tid])       + pos_emb[pb + tid];
    out[ob + tid + 256] = g * acc1 + bf2f(Y[ob + tid + 256]) + pos_emb[pb + tid + 256];
    out[ob + tid + 512] = g * acc2 + bf2f(Y[ob + tid + 512]) + pos_emb[pb + tid + 512];
}

extern "C" void kernel_launch(void* const* d_in, const int* in_sizes, int n_in,
                              void* d_out, int out_size, void* d_ws, size_t ws_size,
                              hipStream_t stream) {
    const float* x       = (const float*)d_in[0];
    const float* patch_w = (const float*)d_in[1];
    const float* patch_b = (const float*)d_in[2];
    const float* wq      = (const float*)d_in[3];
    const float* bq      = (const float*)d_in[4];
    const float* wk      = (const float*)d_in[5];
    const float* bk      = (const float*)d_in[6];
    const float* wv      = (const float*)d_in[7];
    const float* bv      = (const float*)d_in[8];
    const float* gamma   = (const float*)d_in[9];
    const float* pos_emb = (const float*)d_in[10];
    float* out = (float*)d_out;

    char* ws = (char*)d_ws;
    size_t off = 0;
    auto alloc = [&](size_t bytes) { char* pp = ws + off; off += (bytes + 255) & ~(size_t)255; return pp; };
    unsigned short* A1  = (unsigned short*)alloc((size_t)MROWS * KDIM * 2);  // im2col; later reused as V
    unsigned short* Y   = (unsigned short*)alloc((size_t)MROWS * HID * 2);
    unsigned short* QKb = (unsigned short*)alloc((size_t)MROWS * 256 * 2);
    unsigned short* Wp  = (unsigned short*)alloc((size_t)HID * HID * 2);
    unsigned short* Wqk = (unsigned short*)alloc((size_t)256 * HID * 2);
    unsigned short* Wv  = (unsigned short*)alloc((size_t)HID * HID * 2);
    float*          Bqk = (float*)alloc(256 * 4);
    unsigned short* V   = A1;   // alias: A1 is dead after GEMM1

    k_im2col<<<dim3((MROWS * KDIM / 4 + 255) / 256), dim3(256), 0, stream>>>(x, A1);
    k_prep<<<dim3((HID * HID + 255) / 256), dim3(256), 0, stream>>>(patch_w, wq, wk, wv, bq, bk, Wp, Wqk, Wv, Bqk);
    // y = im2col(x) @ patch_w^T + patch_b
    k_gemm_bt<<<dim3(MROWS / 128, HID / 128), dim3(256), 0, stream>>>(A1, Wp, patch_b, Y, MROWS, HID, KDIM);
    // qk = y @ [wq;wk;0]^T + [bq;bk;0]
    k_gemm_bt<<<dim3(MROWS / 128, 256 / 128), dim3(256), 0, stream>>>(Y, Wqk, Bqk, QKb, MROWS, 256, HID);
    // v = y @ wv^T + bv   (writes into A1 space)
    k_gemm_bt<<<dim3(MROWS / 128, HID / 128), dim3(256), 0, stream>>>(Y, Wv, bv, V, MROWS, HID, HID);
    // attention + residual + pos_emb
    k_attn<<<dim3(MROWS), dim3(256), 0, stream>>>(QKb, V, Y, gamma, pos_emb, out);
}

// Round 2
// 339.492 us; speedup vs baseline: 1.3303x; 1.3303x over previous
//
#include <hip/hip_runtime.h>
#include <hip/hip_bf16.h>
#include <cstdint>

#define BATCH 64
#define CIN 3
#define IMG 384
#define PATCH 16
#define HID 768
#define CQ 96
#define HW24 24
#define NP 576
#define MROWS (BATCH*NP)   /* 36864 */
#define KDIM 768           /* = CIN*PATCH*PATCH = HID */
#define NVQK 1024          /* V(768) + Q(96) + K(96) + pad(64) */
#define NEGINF (-1e30f)

typedef __attribute__((ext_vector_type(8))) short s16x8;
typedef __attribute__((ext_vector_type(4))) float f32x4;

__device__ __forceinline__ float bf2f(unsigned short u) {
    union { unsigned int i; float f; } x; x.i = ((unsigned int)u) << 16; return x.f;
}
__device__ __forceinline__ unsigned short f2bf(float f) {
    union { float f; unsigned int i; } x; x.f = f;
    unsigned int r = x.i + 0x7fffu + ((x.i >> 16) & 1u);
    return (unsigned short)(r >> 16);
}

__device__ __forceinline__ void gload_lds16(const void* g, void* l) {
    __builtin_amdgcn_global_load_lds(
        (const __attribute__((address_space(1))) void*)(uintptr_t)g,
        (__attribute__((address_space(3))) void*)(uint32_t)(uintptr_t)l,
        16, 0, 0);
}

// ---------------- im2col: x (B,3,384,384) f32 -> A (36864 x 768) bf16 ----------------
__global__ void k_im2col(const float* __restrict__ x, unsigned short* __restrict__ A) {
    int idx = blockIdx.x * 256 + threadIdx.x;
    const int total = MROWS * KDIM / 4;
    if (idx >= total) return;
    int flat = idx * 4;
    int r = flat / KDIM;
    int cij = flat - r * KDIM;
    int b = r / NP;
    int p = r - b * NP;
    int ph = p / HW24, pw = p - ph * HW24;
    int c = cij >> 8;
    int rem = cij & 255;
    int i = rem >> 4, j = rem & 15;
    size_t xoff = (((size_t)(b * CIN + c) * IMG) + (size_t)(ph * PATCH + i)) * IMG + pw * PATCH + j;
    float4 v = *reinterpret_cast<const float4*>(x + xoff);
    ushort4 o;
    o.x = f2bf(v.x); o.y = f2bf(v.y); o.z = f2bf(v.z); o.w = f2bf(v.w);
    *reinterpret_cast<ushort4*>(A + flat) = o;
}

// ---------------- weight prep: Wp[768][768]; Wvqk[1024][768] = [wv; wq; wk; 0] ----------------
__global__ void k_prep(const float* __restrict__ pw, const float* __restrict__ wq,
                       const float* __restrict__ wk, const float* __restrict__ wv,
                       const float* __restrict__ bq, const float* __restrict__ bk,
                       const float* __restrict__ bv,
                       unsigned short* __restrict__ Wp, unsigned short* __restrict__ Wvqk,
                       float* __restrict__ Bvqk) {
    int t = blockIdx.x * 256 + threadIdx.x;
    if (t < HID * HID) Wp[t] = f2bf(pw[t]);
    if (t < NVQK * HID) {
        int row = t / HID; int col = t - row * HID;
        float val = 0.f;
        if (row < 768) val = wv[t];
        else if (row < 864) val = wq[(row - 768) * HID + col];
        else if (row < 960) val = wk[(row - 864) * HID + col];
        Wvqk[t] = f2bf(val);
    }
    if (t < NVQK) {
        float v = 0.f;
        if (t < 768) v = bv[t]; else if (t < 864) v = bq[t - 768]; else if (t < 960) v = bk[t - 864];
        Bvqk[t] = v;
    }
}

// ---------------- bf16 GEMM:  C[M][N] = A[M][K] * Bw[N][K]^T + bias[N]   (m97 structure) ----------------
__global__ __launch_bounds__(256) void k_gemm_bt(
    const unsigned short* __restrict__ A, const unsigned short* __restrict__ Bw,
    const float* __restrict__ bias, unsigned short* __restrict__ C,
    int M, int N, int K)
{
    __shared__ unsigned short lA[128 * 32];
    __shared__ unsigned short lB[128 * 32];
    const int tid  = threadIdx.x;
    const int lane = tid & 63;
    const int wid  = tid >> 6;
    const int wr = (wid >> 1) << 6;
    const int wc = (wid & 1) << 6;
    const int srow = tid >> 2;
    const int scol = (tid & 3) << 3;

    const unsigned short* gA = A + (size_t)(blockIdx.x * 128 + srow) * K + scol;
    const unsigned short* gB = Bw + (size_t)(blockIdx.y * 128 + srow) * K + scol;
    unsigned short* dA0 = &lA[tid * 8];
    unsigned short* dA1 = &lA[tid * 8 + 64 * 32];
    unsigned short* dB0 = &lB[tid * 8];
    unsigned short* dB1 = &lB[tid * 8 + 64 * 32];

    const int abase = (wr + (lane & 15)) * 32 + (lane >> 4) * 8;
    const int bbase = (wc + (lane & 15)) * 32 + (lane >> 4) * 8;

    f32x4 acc[4][4] = {};

    for (int kk = 0; kk < K; kk += 32) {
        gload_lds16(gA, dA0);
        gload_lds16(gA + (size_t)64 * K, dA1);
        gload_lds16(gB, dB0);
        gload_lds16(gB + (size_t)64 * K, dB1);
        gA += 32; gB += 32;
        __syncthreads();

        s16x8 af[4], bf[4];
        #pragma unroll
        for (int m = 0; m < 4; m++) af[m] = *(const s16x8*)&lA[abase + m * 16 * 32];
        #pragma unroll
        for (int n = 0; n < 4; n++) bf[n] = *(const s16x8*)&lB[bbase + n * 16 * 32];

        #pragma unroll
        for (int m = 0; m < 4; m++)
            #pragma unroll
            for (int n = 0; n < 4; n++)
                acc[m][n] = __builtin_amdgcn_mfma_f32_16x16x32_bf16(af[m], bf[n], acc[m][n], 0, 0, 0);
        __syncthreads();
    }

    const int colbase = blockIdx.y * 128 + wc + (lane & 15);
    const int rowbase = blockIdx.x * 128 + wr + ((lane >> 4) << 2);
    #pragma unroll
    for (int n = 0; n < 4; n++) {
        int col = colbase + n * 16;
        float bs = bias[col];
        #pragma unroll
        for (int m = 0; m < 4; m++) {
            int row = rowbase + m * 16;
            #pragma unroll
            for (int r2 = 0; r2 < 4; r2++) {
                C[(size_t)(row + r2) * N + col] = f2bf(acc[m][n][r2] + bs);
            }
        }
    }
}

// ---------------- energies H: block per (b,w); E[p*48 + j] = q_i . k_j (col w), mask i==j ----------------
__global__ __launch_bounds__(256) void k_energyH(const unsigned short* __restrict__ VQK,
                                                 float* __restrict__ E) {
    __shared__ float qs[24][97], ks[24][97];
    const int b = blockIdx.x / HW24, w = blockIdx.x % HW24;
    const int tid = threadIdx.x;
    for (int idx = tid; idx < 24 * 12; idx += 256) {
        int i = idx / 12, c = (idx % 12) * 8;
        size_t base = ((size_t)(b * NP + i * HW24 + w)) * NVQK + 768;
        s16x8 qv = *(const s16x8*)(VQK + base + c);
        s16x8 kv = *(const s16x8*)(VQK + base + 96 + c);
        #pragma unroll
        for (int u = 0; u < 8; u++) {
            qs[i][c + u] = bf2f((unsigned short)qv[u]);
            ks[i][c + u] = bf2f((unsigned short)kv[u]);
        }
    }
    __syncthreads();
    for (int idx = tid; idx < 576; idx += 256) {
        int i = idx / 24, j = idx - (idx / 24) * 24;
        float s = NEGINF;
        if (i != j) {
            s = 0.f;
            #pragma unroll 8
            for (int c = 0; c < 96; c++) s += qs[i][c] * ks[j][c];
        }
        E[((size_t)(b * NP + i * HW24 + w)) * 48 + j] = s;
    }
}

// ---------------- energies W + softmax: block per (b,h) ----------------
__global__ __launch_bounds__(256) void k_energyW(const unsigned short* __restrict__ VQK,
                                                 float* __restrict__ E) {
    __shared__ float qs[24][97], ks[24][97], ew[24][24];
    const int b = blockIdx.x / HW24, h = blockIdx.x % HW24;
    const int tid = threadIdx.x;
    const int prow = b * NP + h * HW24;
    for (int idx = tid; idx < 24 * 12; idx += 256) {
        int i = idx / 12, c = (idx % 12) * 8;
        size_t base = ((size_t)(prow + i)) * NVQK + 768;
        s16x8 qv = *(const s16x8*)(VQK + base + c);
        s16x8 kv = *(const s16x8*)(VQK + base + 96 + c);
        #pragma unroll
        for (int u = 0; u < 8; u++) {
            qs[i][c + u] = bf2f((unsigned short)qv[u]);
            ks[i][c + u] = bf2f((unsigned short)kv[u]);
        }
    }
    __syncthreads();
    for (int idx = tid; idx < 576; idx += 256) {
        int i = idx / 24, j = idx - (idx / 24) * 24;
        float s = 0.f;
        #pragma unroll 8
        for (int c = 0; c < 96; c++) s += qs[i][c] * ks[j][c];
        ew[i][j] = s;
    }
    __syncthreads();
    if (tid < 24) {
        size_t p = prow + tid;
        float e[48];
        #pragma unroll
        for (int j = 0; j < 24; j++) e[j] = E[p * 48 + j];
        #pragma unroll
        for (int j = 0; j < 24; j++) e[24 + j] = ew[tid][j];
        float mx = NEGINF;
        #pragma unroll
        for (int j = 0; j < 48; j++) mx = fmaxf(mx, e[j]);
        float sum = 0.f;
        #pragma unroll
        for (int j = 0; j < 48; j++) { e[j] = __expf(e[j] - mx); sum += e[j]; }
        float inv = 1.f / sum;
        #pragma unroll
        for (int j = 0; j < 48; j++) E[p * 48 + j] = e[j] * inv;
    }
}

// ---------------- pass H: block per (b,w) swizzled; out = g*out_H + y + pos ----------------
__global__ __launch_bounds__(192) void k_passH(const float* __restrict__ E,
        const unsigned short* __restrict__ VQK, const unsigned short* __restrict__ Y,
        const float* __restrict__ gamma, const float* __restrict__ pos,
        float* __restrict__ out) {
    __shared__ float att[576];
    int bid = (blockIdx.x & 7) * 192 + (blockIdx.x >> 3);   // XCD chunk swizzle (1536 = 8*192)
    const int b = bid / HW24, w = bid % HW24;
    const int tid = threadIdx.x;
    for (int idx = tid; idx < 576; idx += 192) {
        int i = idx / 24, j = idx - (idx / 24) * 24;
        att[idx] = E[((size_t)(b * NP + i * HW24 + w)) * 48 + j];
    }
    __syncthreads();
    float vf[24][4];
    #pragma unroll
    for (int j = 0; j < 24; j++) {
        ushort4 vv = *(const ushort4*)(VQK + ((size_t)(b * NP + j * HW24 + w)) * NVQK + 4 * tid);
        vf[j][0] = bf2f(vv.x); vf[j][1] = bf2f(vv.y); vf[j][2] = bf2f(vv.z); vf[j][3] = bf2f(vv.w);
    }
    const float g = gamma[0];
    #pragma unroll
    for (int i = 0; i < 24; i++) {
        float a0 = 0.f, a1 = 0.f, a2 = 0.f, a3 = 0.f;
        #pragma unroll
        for (int j = 0; j < 24; j++) {
            float a = att[i * 24 + j];
            a0 += a * vf[j][0]; a1 += a * vf[j][1]; a2 += a * vf[j][2]; a3 += a * vf[j][3];
        }
        size_t p = (size_t)(b * NP + i * HW24 + w);
        ushort4 yv = *(const ushort4*)(Y + p * HID + 4 * tid);
        float4 pv = *(const float4*)(pos + (size_t)(i * HW24 + w) * HID + 4 * tid);
        float4 o;
        o.x = g * a0 + bf2f(yv.x) + pv.x;
        o.y = g * a1 + bf2f(yv.y) + pv.y;
        o.z = g * a2 + bf2f(yv.z) + pv.z;
        o.w = g * a3 + bf2f(yv.w) + pv.w;
        *reinterpret_cast<float4*>(out + p * HID + 4 * tid) = o;
    }
}

// ---------------- pass W: block per (b,h) swizzled; out += g*out_W ----------------
__global__ __launch_bounds__(192) void k_passW(const float* __restrict__ E,
        const unsigned short* __restrict__ VQK, const float* __restrict__ gamma,
        float* __restrict__ out) {
    __shared__ float att[576];
    int bid = (blockIdx.x & 7) * 192 + (blockIdx.x >> 3);
    const int b = bid / HW24, h = bid % HW24;
    const int tid = threadIdx.x;
    const int prow = b * NP + h * HW24;
    for (int idx = tid; idx < 576; idx += 192) {
        int i = idx / 24, j = idx - (idx / 24) * 24;
        att[idx] = E[((size_t)(prow + i)) * 48 + 24 + j];
    }
    __syncthreads();
    float vf[24][4];
    #pragma unroll
    for (int j = 0; j < 24; j++) {
        ushort4 vv = *(const ushort4*)(VQK + ((size_t)(prow + j)) * NVQK + 4 * tid);
        vf[j][0] = bf2f(vv.x); vf[j][1] = bf2f(vv.y); vf[j][2] = bf2f(vv.z); vf[j][3] = bf2f(vv.w);
    }
    const float g = gamma[0];
    #pragma unroll
    for (int i = 0; i < 24; i++) {
        float a0 = 0.f, a1 = 0.f, a2 = 0.f, a3 = 0.f;
        #pragma unroll
        for (int j = 0; j < 24; j++) {
            float a = att[i * 24 + j];
            a0 += a * vf[j][0]; a1 += a * vf[j][1]; a2 += a * vf[j][2]; a3 += a * vf[j][3];
        }
        size_t p = (size_t)(prow + i);
        float4 o = *reinterpret_cast<const float4*>(out + p * HID + 4 * tid);
        o.x += g * a0; o.y += g * a1; o.z += g * a2; o.w += g * a3;
        *reinterpret_cast<float4*>(out + p * HID + 4 * tid) = o;
    }
}

extern "C" void kernel_launch(void* const* d_in, const int* in_sizes, int n_in,
                              void* d_out, int out_size, void* d_ws, size_t ws_size,
                              hipStream_t stream) {
    const float* x       = (const float*)d_in[0];
    const float* patch_w = (const float*)d_in[1];
    const float* patch_b = (const float*)d_in[2];
    const float* wq      = (const float*)d_in[3];
    const float* bq      = (const float*)d_in[4];
    const float* wk      = (const float*)d_in[5];
    const float* bk      = (const float*)d_in[6];
    const float* wv      = (const float*)d_in[7];
    const float* bv      = (const float*)d_in[8];
    const float* gamma   = (const float*)d_in[9];
    const float* pos_emb = (const float*)d_in[10];
    float* out = (float*)d_out;

    char* ws = (char*)d_ws;
    size_t off = 0;
    auto alloc = [&](size_t bytes) { char* pp = ws + off; off += (bytes + 255) & ~(size_t)255; return pp; };
    unsigned short* VQK = (unsigned short*)alloc((size_t)MROWS * NVQK * 2); // 75.5 MB; first 56.6 MB doubles as im2col A
    unsigned short* Y   = (unsigned short*)alloc((size_t)MROWS * HID * 2);  // 56.6 MB
    unsigned short* Wp  = (unsigned short*)alloc((size_t)HID * HID * 2);
    unsigned short* Wvqk= (unsigned short*)alloc((size_t)NVQK * HID * 2);
    float*          Bvqk= (float*)alloc(NVQK * 4);
    float*          E   = (float*)alloc((size_t)MROWS * 48 * 4);            // 7.1 MB
    unsigned short* A1  = VQK;  // im2col output; dead after GEMM1, then VQK overwrites

    k_im2col<<<dim3((MROWS * KDIM / 4 + 255) / 256), dim3(256), 0, stream>>>(x, A1);
    k_prep<<<dim3((NVQK * HID + 255) / 256), dim3(256), 0, stream>>>(patch_w, wq, wk, wv, bq, bk, bv, Wp, Wvqk, Bvqk);
    // y = im2col(x) @ patch_w^T + patch_b
    k_gemm_bt<<<dim3(MROWS / 128, HID / 128), dim3(256), 0, stream>>>(A1, Wp, patch_b, Y, MROWS, HID, KDIM);
    // [v | q | k | 0] = y @ Wvqk^T + Bvqk
    k_gemm_bt<<<dim3(MROWS / 128, NVQK / 128), dim3(256), 0, stream>>>(Y, Wvqk, Bvqk, VQK, MROWS, NVQK, HID);
    // criss-cross attention
    k_energyH<<<dim3(BATCH * HW24), dim3(256), 0, stream>>>(VQK, E);
    k_energyW<<<dim3(BATCH * HW24), dim3(256), 0, stream>>>(VQK, E);
    k_passH<<<dim3(BATCH * HW24), dim3(192), 0, stream>>>(E, VQK, Y, gamma, pos_emb, out);
    k_passW<<<dim3(BATCH * HW24), dim3(192), 0, stream>>>(E, VQK, gamma, out);
}

// Round 3
// 325.135 us; speedup vs baseline: 1.3891x; 1.0442x over previous
//
#include <hip/hip_runtime.h>
#include <hip/hip_bf16.h>
#include <cstdint>

#define BATCH 64
#define CIN 3
#define IMG 384
#define PATCH 16
#define HID 768
#define CQ 96
#define HW24 24
#define NP 576
#define MROWS (BATCH*NP)   /* 36864 */
#define KDIM 768           /* = CIN*PATCH*PATCH = HID */
#define NVQK 1024          /* V(768) + Q(96) + K(96) + pad(64) */
#define NT_K 12            /* 768 / 64 K-tiles */
#define NEGINF (-1e30f)

typedef __attribute__((ext_vector_type(8))) short s16x8;
typedef __attribute__((ext_vector_type(4))) float f32x4;

__device__ __forceinline__ float bf2f(unsigned short u) {
    union { unsigned int i; float f; } x; x.i = ((unsigned int)u) << 16; return x.f;
}
__device__ __forceinline__ unsigned short f2bf(float f) {
    union { float f; unsigned int i; } x; x.f = f;
    unsigned int r = x.i + 0x7fffu + ((x.i >> 16) & 1u);
    return (unsigned short)(r >> 16);
}

__device__ __forceinline__ void gload_lds16(const void* g, void* l) {
    __builtin_amdgcn_global_load_lds(
        (const __attribute__((address_space(1))) void*)(uintptr_t)g,
        (__attribute__((address_space(3))) void*)(uint32_t)(uintptr_t)l,
        16, 0, 0);
}

// ---------------- im2col: x (B,3,384,384) f32 -> A (36864 x 768) bf16 ----------------
__global__ void k_im2col(const float* __restrict__ x, unsigned short* __restrict__ A) {
    int idx = blockIdx.x * 256 + threadIdx.x;
    const int total = MROWS * KDIM / 4;
    if (idx >= total) return;
    int flat = idx * 4;
    int r = flat / KDIM;
    int cij = flat - r * KDIM;
    int b = r / NP;
    int p = r - b * NP;
    int ph = p / HW24, pw = p - ph * HW24;
    int c = cij >> 8;
    int rem = cij & 255;
    int i = rem >> 4, j = rem & 15;
    size_t xoff = (((size_t)(b * CIN + c) * IMG) + (size_t)(ph * PATCH + i)) * IMG + pw * PATCH + j;
    float4 v = *reinterpret_cast<const float4*>(x + xoff);
    ushort4 o;
    o.x = f2bf(v.x); o.y = f2bf(v.y); o.z = f2bf(v.z); o.w = f2bf(v.w);
    *reinterpret_cast<ushort4*>(A + flat) = o;
}

// ---------------- weight prep ----------------
__global__ void k_prep(const float* __restrict__ pw, const float* __restrict__ wq,
                       const float* __restrict__ wk, const float* __restrict__ wv,
                       const float* __restrict__ bq, const float* __restrict__ bk,
                       const float* __restrict__ bv,
                       unsigned short* __restrict__ Wp, unsigned short* __restrict__ Wvqk,
                       float* __restrict__ Bvqk) {
    int t = blockIdx.x * 256 + threadIdx.x;
    if (t < HID * HID) Wp[t] = f2bf(pw[t]);
    if (t < NVQK * HID) {
        int row = t / HID; int col = t - row * HID;
        float val = 0.f;
        if (row < 768) val = wv[t];
        else if (row < 864) val = wq[(row - 768) * HID + col];
        else if (row < 960) val = wk[(row - 864) * HID + col];
        Wvqk[t] = f2bf(val);
    }
    if (t < NVQK) {
        float v = 0.f;
        if (t < 768) v = bv[t]; else if (t < 864) v = bq[t - 768]; else if (t < 960) v = bk[t - 864];
        Bvqk[t] = v;
    }
}

// ============ 256x256x64 8-phase bf16 GEMM:  C[M][N] = A[M][K=768] * Bw[N][K=768]^T + bias ============
// 512 threads = 8 waves (2M x 4N). LDS 128KB: buf{0,1} x [A 256x64 (32KB) | B 256x64 (32KB)].
// LDS rows 128B, XOR-swizzled: byte_in_row ^= (row&7)<<4.  Staged linear-dest w/ pre-swizzled source.
__device__ __forceinline__ void stage_half(const unsigned short* __restrict__ gmat,
        int growbase, char* ldsregion, int kcol, int rl, int sp, int ldsoff0) {
    const unsigned short* g0 = gmat + (size_t)(growbase + rl) * KDIM + kcol + sp * 8;
    gload_lds16(g0, ldsregion + ldsoff0);
    const unsigned short* g1 = g0 + (size_t)8 * KDIM;
    gload_lds16(g1, ldsregion + ldsoff0 + 1024);
}

__global__ __launch_bounds__(512, 2) void k_gemm256(
    const unsigned short* __restrict__ A, const unsigned short* __restrict__ Bw,
    const float* __restrict__ bias, unsigned short* __restrict__ C,
    int MT, int N)
{
    extern __shared__ char smem[];
    const int tid  = threadIdx.x;
    const int lane = tid & 63;
    const int w    = tid >> 6;
    const int wm   = w >> 2;   // 0..1
    const int wn   = w & 3;    // 0..3

    // bijective XCD chunk swizzle (nwg % 8 == 0 for both GEMMs)
    const int nwg = gridDim.x;
    const int chunk = nwg >> 3;
    const int bid = blockIdx.x;
    const int bs = (bid & 7) * chunk + (bid >> 3);
    const int bx = bs % MT, by = bs / MT;
    const int blockM = bx << 8;
    const int blockN = by << 8;

    // staging lane constants: thread covers rows rl, rl+8 of the half; slot sp (inverse-swizzled)
    const int rl = (w << 4) + (lane >> 3);
    const int sp = (lane & 7) ^ (lane >> 3);
    const int ldsoff0 = (w << 11) + (lane << 4);

    // ds_read lane constants
    const int lx   = (lane & 15) << 7;               // row-within-frag * 128B
    const int swz  = (lane & 7) << 4;
    const int cbx0 = (((lane >> 4) << 4)) ^ swz;     // kh=0
    const int cbx1 = (64 + ((lane >> 4) << 4)) ^ swz;// kh=1

    // prologue: tile0 {B0,B1,A0,A1}, tile1 {B0,B1}
    stage_half(Bw, blockN,       smem + 32768, 0, rl, sp, ldsoff0);
    stage_half(Bw, blockN + 128, smem + 49152, 0, rl, sp, ldsoff0);
    stage_half(A,  blockM,       smem,         0, rl, sp, ldsoff0);
    stage_half(A,  blockM + 128, smem + 16384, 0, rl, sp, ldsoff0);
    stage_half(Bw, blockN,       smem + 65536 + 32768, 64, rl, sp, ldsoff0);
    stage_half(Bw, blockN + 128, smem + 65536 + 49152, 64, rl, sp, ldsoff0);

    f32x4 acc[8][4] = {};

    asm volatile("s_waitcnt vmcnt(4)" ::: "memory");
    __builtin_amdgcn_sched_barrier(0);
    __builtin_amdgcn_s_barrier();

    for (int t = 0; t < NT_K; ++t) {
        char* sA = smem + ((t & 1) << 16);
        char* sB = sA + 32768;
        s16x8 bfr[4][2];
        #pragma unroll
        for (int q = 0; q < 4; ++q) {
            // ---- stage slot (strictly after the region's last-reader barrier) ----
            if (q == 0) {
                if (t + 1 < NT_K) {     // A halves of tile t+1 -> other buffer (its A reads ended last tile)
                    char* nb = smem + (((t + 1) & 1) << 16);
                    const int kc = (t + 1) << 6;
                    stage_half(A, blockM,       nb,         kc, rl, sp, ldsoff0);
                    stage_half(A, blockM + 128, nb + 16384, kc, rl, sp, ldsoff0);
                }
            } else if (q == 1) {
                if (t + 2 < NT_K)       // B0 of tile t+2 -> this buffer (B fully read in q0)
                    stage_half(Bw, blockN,       sB,         (t + 2) << 6, rl, sp, ldsoff0);
            } else if (q == 2) {
                if (t + 2 < NT_K)
                    stage_half(Bw, blockN + 128, sB + 16384, (t + 2) << 6, rl, sp, ldsoff0);
            }
            // ---- ds_reads for this phase ----
            s16x8 afr[2][2];
            {
                const int rb0 = wm * 16384 + (q * 2) * 2048 + lx;
                afr[0][0] = *(const s16x8*)(sA + rb0 + cbx0);
                afr[0][1] = *(const s16x8*)(sA + rb0 + cbx1);
                afr[1][0] = *(const s16x8*)(sA + rb0 + 2048 + cbx0);
                afr[1][1] = *(const s16x8*)(sA + rb0 + 2048 + cbx1);
            }
            if (q == 0) {
                #pragma unroll
                for (int nf = 0; nf < 4; ++nf) {
                    const int rb = wn * 8192 + nf * 2048 + lx;
                    bfr[nf][0] = *(const s16x8*)(sB + rb + cbx0);
                    bfr[nf][1] = *(const s16x8*)(sB + rb + cbx1);
                }
            }
            __builtin_amdgcn_s_barrier();
            asm volatile("s_waitcnt lgkmcnt(0)" ::: "memory");
            __builtin_amdgcn_sched_barrier(0);
            __builtin_amdgcn_s_setprio(1);
            #pragma unroll
            for (int i = 0; i < 2; ++i)
                #pragma unroll
                for (int nf = 0; nf < 4; ++nf)
                    #pragma unroll
                    for (int kh = 0; kh < 2; ++kh)
                        acc[q * 2 + i][nf] = __builtin_amdgcn_mfma_f32_16x16x32_bf16(
                            bfr[nf][kh], afr[i][kh], acc[q * 2 + i][nf], 0, 0, 0);
            __builtin_amdgcn_s_setprio(0);
            if (q == 3) {
                asm volatile("s_waitcnt vmcnt(4)" ::: "memory");  // tile t+1 fully landed
                __builtin_amdgcn_sched_barrier(0);
            }
            __builtin_amdgcn_s_barrier();
        }
    }

    // epilogue: D col(lane&15) = M-row, D row((lane>>4)*4+reg) = N-col (operands swapped) -> ushort4 packs 4 N
    const int rowb = blockM + wm * 128 + (lane & 15);
    const int colb = blockN + wn * 64 + ((lane >> 4) << 2);
    #pragma unroll
    for (int mf = 0; mf < 8; ++mf) {
        const int row = rowb + mf * 16;
        #pragma unroll
        for (int nf = 0; nf < 4; ++nf) {
            const int col = colb + nf * 16;
            float4 bs4 = *(const float4*)(bias + col);
            f32x4 a = acc[mf][nf];
            ushort4 o;
            o.x = f2bf(a[0] + bs4.x);
            o.y = f2bf(a[1] + bs4.y);
            o.z = f2bf(a[2] + bs4.z);
            o.w = f2bf(a[3] + bs4.w);
            *reinterpret_cast<ushort4*>(C + (size_t)row * N + col) = o;
        }
    }
}

// ---------------- energies H: block per (b,w); E[p*48 + j] = q_i . k_j (col w), mask i==j ----------------
__global__ __launch_bounds__(256) void k_energyH(const unsigned short* __restrict__ VQK,
                                                 float* __restrict__ E) {
    __shared__ float qs[24][97], ks[24][97];
    const int b = blockIdx.x / HW24, w = blockIdx.x % HW24;
    const int tid = threadIdx.x;
    for (int idx = tid; idx < 24 * 12; idx += 256) {
        int i = idx / 12, c = (idx % 12) * 8;
        size_t base = ((size_t)(b * NP + i * HW24 + w)) * NVQK + 768;
        s16x8 qv = *(const s16x8*)(VQK + base + c);
        s16x8 kv = *(const s16x8*)(VQK + base + 96 + c);
        #pragma unroll
        for (int u = 0; u < 8; u++) {
            qs[i][c + u] = bf2f((unsigned short)qv[u]);
            ks[i][c + u] = bf2f((unsigned short)kv[u]);
        }
    }
    __syncthreads();
    for (int idx = tid; idx < 576; idx += 256) {
        int i = idx / 24, j = idx - (idx / 24) * 24;
        float s = NEGINF;
        if (i != j) {
            s = 0.f;
            #pragma unroll 8
            for (int c = 0; c < 96; c++) s += qs[i][c] * ks[j][c];
        }
        E[((size_t)(b * NP + i * HW24 + w)) * 48 + j] = s;
    }
}

// ---------------- energies W + softmax: block per (b,h) ----------------
__global__ __launch_bounds__(256) void k_energyW(const unsigned short* __restrict__ VQK,
                                                 float* __restrict__ E) {
    __shared__ float qs[24][97], ks[24][97], ew[24][24];
    const int b = blockIdx.x / HW24, h = blockIdx.x % HW24;
    const int tid = threadIdx.x;
    const int prow = b * NP + h * HW24;
    for (int idx = tid; idx < 24 * 12; idx += 256) {
        int i = idx / 12, c = (idx % 12) * 8;
        size_t base = ((size_t)(prow + i)) * NVQK + 768;
        s16x8 qv = *(const s16x8*)(VQK + base + c);
        s16x8 kv = *(const s16x8*)(VQK + base + 96 + c);
        #pragma unroll
        for (int u = 0; u < 8; u++) {
            qs[i][c + u] = bf2f((unsigned short)qv[u]);
            ks[i][c + u] = bf2f((unsigned short)kv[u]);
        }
    }
    __syncthreads();
    for (int idx = tid; idx < 576; idx += 256) {
        int i = idx / 24, j = idx - (idx / 24) * 24;
        float s = 0.f;
        #pragma unroll 8
        for (int c = 0; c < 96; c++) s += qs[i][c] * ks[j][c];
        ew[i][j] = s;
    }
    __syncthreads();
    if (tid < 24) {
        size_t p = prow + tid;
        float e[48];
        #pragma unroll
        for (int j = 0; j < 24; j++) e[j] = E[p * 48 + j];
        #pragma unroll
        for (int j = 0; j < 24; j++) e[24 + j] = ew[tid][j];
        float mx = NEGINF;
        #pragma unroll
        for (int j = 0; j < 48; j++) mx = fmaxf(mx, e[j]);
        float sum = 0.f;
        #pragma unroll
        for (int j = 0; j < 48; j++) { e[j] = __expf(e[j] - mx); sum += e[j]; }
        float inv = 1.f / sum;
        #pragma unroll
        for (int j = 0; j < 48; j++) E[p * 48 + j] = e[j] * inv;
    }
}

// ---------------- pass H: block per (b,w) swizzled; out = g*out_H + y + pos ----------------
__global__ __launch_bounds__(192) void k_passH(const float* __restrict__ E,
        const unsigned short* __restrict__ VQK, const unsigned short* __restrict__ Y,
        const float* __restrict__ gamma, const float* __restrict__ pos,
        float* __restrict__ out) {
    __shared__ float att[576];
    int bid = (blockIdx.x & 7) * 192 + (blockIdx.x >> 3);
    const int b = bid / HW24, w = bid % HW24;
    const int tid = threadIdx.x;
    for (int idx = tid; idx < 576; idx += 192) {
        int i = idx / 24, j = idx - (idx / 24) * 24;
        att[idx] = E[((size_t)(b * NP + i * HW24 + w)) * 48 + j];
    }
    __syncthreads();
    float vf[24][4];
    #pragma unroll
    for (int j = 0; j < 24; j++) {
        ushort4 vv = *(const ushort4*)(VQK + ((size_t)(b * NP + j * HW24 + w)) * NVQK + 4 * tid);
        vf[j][0] = bf2f(vv.x); vf[j][1] = bf2f(vv.y); vf[j][2] = bf2f(vv.z); vf[j][3] = bf2f(vv.w);
    }
    const float g = gamma[0];
    #pragma unroll
    for (int i = 0; i < 24; i++) {
        float a0 = 0.f, a1 = 0.f, a2 = 0.f, a3 = 0.f;
        #pragma unroll
        for (int j = 0; j < 24; j++) {
            float a = att[i * 24 + j];
            a0 += a * vf[j][0]; a1 += a * vf[j][1]; a2 += a * vf[j][2]; a3 += a * vf[j][3];
        }
        size_t p = (size_t)(b * NP + i * HW24 + w);
        ushort4 yv = *(const ushort4*)(Y + p * HID + 4 * tid);
        float4 pv = *(const float4*)(pos + (size_t)(i * HW24 + w) * HID + 4 * tid);
        float4 o;
        o.x = g * a0 + bf2f(yv.x) + pv.x;
        o.y = g * a1 + bf2f(yv.y) + pv.y;
        o.z = g * a2 + bf2f(yv.z) + pv.z;
        o.w = g * a3 + bf2f(yv.w) + pv.w;
        *reinterpret_cast<float4*>(out + p * HID + 4 * tid) = o;
    }
}

// ---------------- pass W: block per (b,h) swizzled; out += g*out_W ----------------
__global__ __launch_bounds__(192) void k_passW(const float* __restrict__ E,
        const unsigned short* __restrict__ VQK, const float* __restrict__ gamma,
        float* __restrict__ out) {
    __shared__ float att[576];
    int bid = (blockIdx.x & 7) * 192 + (blockIdx.x >> 3);
    const int b = bid / HW24, h = bid % HW24;
    const int tid = threadIdx.x;
    const int prow = b * NP + h * HW24;
    for (int idx = tid; idx < 576; idx += 192) {
        int i = idx / 24, j = idx - (idx / 24) * 24;
        att[idx] = E[((size_t)(prow + i)) * 48 + 24 + j];
    }
    __syncthreads();
    float vf[24][4];
    #pragma unroll
    for (int j = 0; j < 24; j++) {
        ushort4 vv = *(const ushort4*)(VQK + ((size_t)(prow + j)) * NVQK + 4 * tid);
        vf[j][0] = bf2f(vv.x); vf[j][1] = bf2f(vv.y); vf[j][2] = bf2f(vv.z); vf[j][3] = bf2f(vv.w);
    }
    const float g = gamma[0];
    #pragma unroll
    for (int i = 0; i < 24; i++) {
        float a0 = 0.f, a1 = 0.f, a2 = 0.f, a3 = 0.f;
        #pragma unroll
        for (int j = 0; j < 24; j++) {
            float a = att[i * 24 + j];
            a0 += a * vf[j][0]; a1 += a * vf[j][1]; a2 += a * vf[j][2]; a3 += a * vf[j][3];
        }
        size_t p = (size_t)(prow + i);
        float4 o = *reinterpret_cast<const float4*>(out + p * HID + 4 * tid);
        o.x += g * a0; o.y += g * a1; o.z += g * a2; o.w += g * a3;
        *reinterpret_cast<float4*>(out + p * HID + 4 * tid) = o;
    }
}

extern "C" void kernel_launch(void* const* d_in, const int* in_sizes, int n_in,
                              void* d_out, int out_size, void* d_ws, size_t ws_size,
                              hipStream_t stream) {
    const float* x       = (const float*)d_in[0];
    const float* patch_w = (const float*)d_in[1];
    const float* patch_b = (const float*)d_in[2];
    const float* wq      = (const float*)d_in[3];
    const float* bq      = (const float*)d_in[4];
    const float* wk      = (const float*)d_in[5];
    const float* bk      = (const float*)d_in[6];
    const float* wv      = (const float*)d_in[7];
    const float* bv      = (const float*)d_in[8];
    const float* gamma   = (const float*)d_in[9];
    const float* pos_emb = (const float*)d_in[10];
    float* out = (float*)d_out;

    hipFuncSetAttribute(reinterpret_cast<const void*>(k_gemm256),
                        hipFuncAttributeMaxDynamicSharedMemorySize, 131072);

    char* ws = (char*)d_ws;
    size_t off = 0;
    auto alloc = [&](size_t bytes) { char* pp = ws + off; off += (bytes + 255) & ~(size_t)255; return pp; };
    unsigned short* VQK = (unsigned short*)alloc((size_t)MROWS * NVQK * 2);
    unsigned short* Y   = (unsigned short*)alloc((size_t)MROWS * HID * 2);
    unsigned short* Wp  = (unsigned short*)alloc((size_t)HID * HID * 2);
    unsigned short* Wvqk= (unsigned short*)alloc((size_t)NVQK * HID * 2);
    float*          Bvqk= (float*)alloc(NVQK * 4);
    float*          E   = (float*)alloc((size_t)MROWS * 48 * 4);
    unsigned short* A1  = VQK;  // im2col output; dead after GEMM1, then VQK overwrites

    k_im2col<<<dim3((MROWS * KDIM / 4 + 255) / 256), dim3(256), 0, stream>>>(x, A1);
    k_prep<<<dim3((NVQK * HID + 255) / 256), dim3(256), 0, stream>>>(patch_w, wq, wk, wv, bq, bk, bv, Wp, Wvqk, Bvqk);
    // y = im2col(x) @ patch_w^T + patch_b          (grid 144*3 = 432, %8==0)
    k_gemm256<<<dim3((MROWS / 256) * (HID / 256)), dim3(512), 131072, stream>>>(A1, Wp, patch_b, Y, MROWS / 256, HID);
    // [v | q | k | 0] = y @ Wvqk^T + Bvqk          (grid 144*4 = 576, %8==0)
    k_gemm256<<<dim3((MROWS / 256) * (NVQK / 256)), dim3(512), 131072, stream>>>(Y, Wvqk, Bvqk, VQK, MROWS / 256, NVQK);
    // criss-cross attention
    k_energyH<<<dim3(BATCH * HW24), dim3(256), 0, stream>>>(VQK, E);
    k_energyW<<<dim3(BATCH * HW24), dim3(256), 0, stream>>>(VQK, E);
    k_passH<<<dim3(BATCH * HW24), dim3(192), 0, stream>>>(E, VQK, Y, gamma, pos_emb, out);
    k_passW<<<dim3(BATCH * HW24), dim3(192), 0, stream>>>(E, VQK, gamma, out);
}